// Round 14
// baseline (269.834 us; speedup 1.0000x reference)
//
#include <hip/hip_runtime.h>
#include <hip/hip_fp16.h>
#include <math.h>

#define HCDIM 128
#define LEAKY 0.2f
#define NBUCK 256
#define CHUNK 2048
#define BCAP 5120  // per-bucket capacity; mean 4100, sigma 64 -> 16-sigma slack
#define TPAD 136   // halves; 272B row stride
#define A1S 40

typedef _Float16 half8 __attribute__((ext_vector_type(8)));
typedef _Float16 hh2 __attribute__((ext_vector_type(2)));
typedef float floatx4 __attribute__((ext_vector_type(4)));

// ================= CSR build: binned counting sort =================
__global__ void convert_w_all_kernel(const float* __restrict__ Wl1, const float* __restrict__ Wr1,
                                     __half* __restrict__ Wcat1,
                                     const float* __restrict__ Wl2, const float* __restrict__ Wr2,
                                     __half* __restrict__ Wcat2,
                                     const float* __restrict__ W1, __half* __restrict__ W1f,
                                     const float* __restrict__ W2, __half* __restrict__ W2f,
                                     int* __restrict__ bucket_cursor) {
    int i = blockIdx.x * 256 + threadIdx.x;  // 0 .. 46079
    if (blockIdx.x == 0) bucket_cursor[threadIdx.x] = 0;
    if (i < 8192) {
        int row = i >> 5, c = i & 31;
        float v = 0.f;
        if (c < 16) v = (row < 128) ? Wl1[row * 16 + c] : Wr1[(row - 128) * 16 + c];
        Wcat1[i] = __float2half(v);
    } else if (i < 40960) {
        int j = i - 8192;
        float v = (j < 128 * HCDIM) ? Wl2[j] : Wr2[j - 128 * HCDIM];
        Wcat2[j] = __float2half(v);
    } else if (i < 45056) {
        int j = i - 40960;
        W1f[j] = __float2half(W1[j]);
    } else if (i < 46080) {
        int j = i - 45056;
        W2f[j] = __float2half(W2[j]);
    }
}

__global__ __launch_bounds__(256) void bin_kernel(
        const int* __restrict__ src, const int* __restrict__ dst,
        const float* __restrict__ eattr, int* __restrict__ bucket_cursor,
        int2* __restrict__ binned, int E) {
    __shared__ int hist[NBUCK];
    __shared__ int hist2[NBUCK];
    __shared__ int gbase[NBUCK];
    int t = threadIdx.x;
    int e0 = blockIdx.x * CHUNK;
    int cnt = min(CHUNK, E - e0);
    hist[t] = 0;
    hist2[t] = 0;
    __syncthreads();
    for (int i = t; i < cnt; i += 256) atomicAdd(&hist[((unsigned)dst[e0 + i]) >> 8], 1);
    __syncthreads();
    if (hist[t]) gbase[t] = atomicAdd(&bucket_cursor[t], hist[t]);
    __syncthreads();
    for (int i = t; i < cnt; i += 256) {
        int d = dst[e0 + i];
        int b = ((unsigned)d) >> 8;
        unsigned sv = (unsigned)src[e0 + i] & 0xFFFFu;
        __half eh = __float2half(eattr[e0 + i]);
        int r = atomicAdd(&hist2[b], 1);
        int2 rec;
        rec.x = (int)(sv | ((unsigned)__half_as_ushort(eh) << 16));
        rec.y = d;
        binned[(size_t)b * BCAP + gbase[b] + r] = rec;
    }
}

__global__ __launch_bounds__(256) void scatter2_kernel(
        const int2* __restrict__ binned, const int* __restrict__ bucket_cursor,
        unsigned* __restrict__ packed, int* __restrict__ row_ptr, int n) {
    __shared__ int bsc[NBUCK];
    __shared__ int degl[NBUCK];
    __shared__ int scn[NBUCK];
    __shared__ int cur[NBUCK];
    int t = threadIdx.x;
    int b = blockIdx.x;
    int n0 = b << 8;
    int nodes = min(256, n - n0);
    size_t sbase = (size_t)b * BCAP;
    int cnt = bucket_cursor[b];
    bsc[t] = bucket_cursor[t];
    degl[t] = 0;
    __syncthreads();
    for (int off = 1; off < NBUCK; off <<= 1) {
        int add = (t >= off) ? bsc[t - off] : 0;
        __syncthreads();
        bsc[t] += add;
        __syncthreads();
    }
    int w0 = bsc[b] - cnt;
    for (int i = t; i < cnt; i += 256) atomicAdd(&degl[binned[sbase + i].y & 255], 1);
    __syncthreads();
    int v = degl[t];
    scn[t] = v;
    __syncthreads();
    for (int off = 1; off < NBUCK; off <<= 1) {
        int add = (t >= off) ? scn[t - off] : 0;
        __syncthreads();
        scn[t] += add;
        __syncthreads();
    }
    int pos0 = w0 + scn[t] - v;
    cur[t] = pos0;
    if (t < nodes) row_ptr[n0 + t] = pos0;
    if (t == nodes - 1 && n0 + nodes == n) row_ptr[n] = w0 + cnt;
    __syncthreads();
    for (int i = t; i < cnt; i += 256) {
        int2 rec = binned[sbase + i];
        int p = atomicAdd(&cur[rec.y & 255], 1);
        packed[p] = (unsigned)rec.x;
    }
}

// ---------------- Layer 1 node transform via MFMA: x[N,16] -> xl, xr (fp16) ----------------
#define T16PAD 40
__global__ __launch_bounds__(256) void transform16_mfma_kernel(
        const float* __restrict__ x, const __half* __restrict__ Wcat1,
        const float* __restrict__ bl, const float* __restrict__ br,
        __half* __restrict__ xl, __half* __restrict__ xr, int n) {
    __shared__ __align__(16) __half ax[64 * T16PAD];
    int t = threadIdx.x;
    int base = blockIdx.x * 64;

    {
        int row = t >> 2, cg = t & 3;
        float4 v;
        if (base + row < n) v = *(const float4*)(x + (size_t)(base + row) * 16 + cg * 4);
        else v = make_float4(0.f, 0.f, 0.f, 0.f);
        __half2* p = (__half2*)&ax[row * T16PAD + cg * 4];
        p[0] = __floats2half2_rn(v.x, v.y);
        p[1] = __floats2half2_rn(v.z, v.w);
        __half2* z = (__half2*)&ax[row * T16PAD + 16 + cg * 4];
        z[0] = __floats2half2_rn(0.f, 0.f);
        z[1] = __floats2half2_rn(0.f, 0.f);
    }
    __syncthreads();

    int wid = t >> 6, l = t & 63;
    int lrow = l & 15, lgr = l >> 4;
    int colbase = wid * 64;

    half8 bfrag[4];
    const __half* wp = Wcat1 + (size_t)(colbase + lrow) * 32 + lgr * 8;
#pragma unroll
    for (int ct = 0; ct < 4; ++ct) bfrag[ct] = *(const half8*)(wp + ct * 16 * 32);

    float bv[4];
#pragma unroll
    for (int ct = 0; ct < 4; ++ct) {
        int col = colbase + ct * 16 + lrow;
        bv[ct] = (col < HCDIM) ? bl[col] : br[col - HCDIM];
    }
    __half* dstp = (colbase < HCDIM) ? xl : xr;
    int cb = (colbase < HCDIM) ? colbase : colbase - HCDIM;

#pragma unroll
    for (int rt = 0; rt < 4; ++rt) {
        half8 afrag = *(const half8*)&ax[(rt * 16 + lrow) * T16PAD + lgr * 8];
        floatx4 acc[4];
#pragma unroll
        for (int ct = 0; ct < 4; ++ct) {
            acc[ct] = (floatx4){0.f, 0.f, 0.f, 0.f};
            acc[ct] = __builtin_amdgcn_mfma_f32_16x16x32_f16(afrag, bfrag[ct], acc[ct], 0, 0, 0);
        }
        int rowb = base + rt * 16 + lgr * 4;
#pragma unroll
        for (int ct = 0; ct < 4; ++ct) {
            int col = cb + ct * 16 + lrow;
#pragma unroll
            for (int r = 0; r < 4; ++r) {
                int node = rowb + r;
                if (node < n) dstp[(size_t)node * HCDIM + col] = __float2half(acc[ct][r] + bv[ct]);
            }
        }
    }
}

// ======== shared edge-aggregation core (node-per-16-lane-group, depth-3) ========
template <int CTRL>
__device__ inline float dpp_radd(float x) {
    int y = __builtin_amdgcn_update_dpp(0, __float_as_int(x), CTRL, 0xF, 0xF, true);
    return x + __int_as_float(y);
}

template <int NMASK>
__device__ inline void edge_update_pk(uint4 rowbits, _Float16 eah, bool valid,
                                      const hh2* __restrict__ xr2,
                                      const hh2* __restrict__ we2,
                                      const hh2* __restrict__ at2,
                                      float& d, float* __restrict__ acc) {
    const hh2* xv2 = (const hh2*)&rowbits;
    float p = 0.f;
#pragma unroll
    for (int q = 0; q < 4; ++q) {
        hh2 m = xv2[q] + xr2[q] + eah * we2[q];
        hh2 lk = __builtin_elementwise_max(m, (_Float16)LEAKY * m);  // leaky_relu(x,0.2)
#if __has_builtin(__builtin_amdgcn_fdot2)
        p = __builtin_amdgcn_fdot2(at2[q], lk, p, false);
#else
        p = fmaf((float)at2[q][0], (float)lk[0], fmaf((float)at2[q][1], (float)lk[1], p));
#endif
    }
    p = dpp_radd<0xB1>(p);   // quad_perm [1,0,3,2]
    p = dpp_radd<0x4E>(p);   // quad_perm [2,3,0,1]
    if constexpr (NMASK == 16) {
        p = dpp_radd<0x124>(p);  // row_ror:4
        p = dpp_radd<0x128>(p);  // row_ror:8
    }
    float w = valid ? __expf(p) : 0.f;
    d += w;
    const _Float16* xvh = (const _Float16*)&rowbits;
#pragma unroll
    for (int k = 0; k < 8; ++k) acc[k] = fmaf(w, (float)xvh[k], acc[k]);
}

__device__ inline _Float16 unpack_ea(unsigned pe) {
    ushort hb = (ushort)(pe >> 16);
    _Float16 r;
    __builtin_memcpy(&r, &hb, 2);
    return r;
}

template <int NMASK>
__device__ inline half8 aggregate_node(int node, int n,
                                       const __half* __restrict__ xlc,
                                       const __half* __restrict__ xr, int c0,
                                       const unsigned* __restrict__ packed,
                                       const int* __restrict__ row_ptr,
                                       const hh2* __restrict__ we2,
                                       const hh2* __restrict__ at2,
                                       const float* __restrict__ b8) {
    int nodec = min(node, n - 1);
    uint4 xrbits = *(const uint4*)(xr + (size_t)nodec * HCDIM + c0);
    const hh2* xr2 = (const hh2*)&xrbits;
    int beg = row_ptr[nodec], end = row_ptr[nodec + 1];
    float d = 0.f, acc[8];
#pragma unroll
    for (int k = 0; k < 8; ++k) acc[k] = 0.f;
    bool has = (node < n) && (end > beg);
    if (has) {
        int last = end - 1;
        bool vA = true, vB = beg + 1 < end;
        bool v1A = beg + 2 < end, v1B = beg + 3 < end;
        unsigned pe0A = packed[beg];
        unsigned pe0B = packed[min(beg + 1, last)];
        unsigned pe1A = packed[min(beg + 2, last)];
        unsigned pe1B = packed[min(beg + 3, last)];
        uint4 r0A = *(const uint4*)(xlc + (size_t)(pe0A & 0xFFFFu) * HCDIM);
        uint4 r0B = *(const uint4*)(xlc + (size_t)(pe0B & 0xFFFFu) * HCDIM);
        uint4 r1A = *(const uint4*)(xlc + (size_t)(pe1A & 0xFFFFu) * HCDIM);
        uint4 r1B = *(const uint4*)(xlc + (size_t)(pe1B & 0xFFFFu) * HCDIM);
        int j = beg;
        while (true) {
            bool v2A = j + 4 < end, v2B = j + 5 < end;
            unsigned pe2A = packed[min(j + 4, last)];
            unsigned pe2B = packed[min(j + 5, last)];
            uint4 r2A = *(const uint4*)(xlc + (size_t)(pe2A & 0xFFFFu) * HCDIM);
            uint4 r2B = *(const uint4*)(xlc + (size_t)(pe2B & 0xFFFFu) * HCDIM);
            edge_update_pk<NMASK>(r0A, unpack_ea(pe0A), vA, xr2, we2, at2, d, acc);
            edge_update_pk<NMASK>(r0B, unpack_ea(pe0B), vB, xr2, we2, at2, d, acc);
            pe0A = pe1A; pe0B = pe1B; r0A = r1A; r0B = r1B; vA = v1A; vB = v1B;
            pe1A = pe2A; pe1B = pe2B; r1A = r2A; r1B = r2B; v1A = v2A; v1B = v2B;
            j += 2;
            if (!vA) break;
        }
    }
    float inv = has ? __frcp_rn(d) : 0.f;
    half8 hv;
#pragma unroll
    for (int k = 0; k < 8; ++k) {
        float v = has ? acc[k] * inv + b8[k] : b8[k];
        v = v > 0.f ? v : expm1f(v);  // ELU
        hv[k] = (_Float16)v;
    }
    return hv;
}

__device__ inline void load_edge_consts(const float* We, const float* att,
                                        const float* bias, int c0,
                                        hh2* we2, hh2* at2, float* b8) {
    float tmp8[8];
    *(float4*)&tmp8[0] = *(const float4*)(We + c0);
    *(float4*)&tmp8[4] = *(const float4*)(We + c0 + 4);
#pragma unroll
    for (int q = 0; q < 4; ++q) {
        we2[q][0] = (_Float16)tmp8[2 * q];
        we2[q][1] = (_Float16)tmp8[2 * q + 1];
    }
    *(float4*)&tmp8[0] = *(const float4*)(att + c0);
    *(float4*)&tmp8[4] = *(const float4*)(att + c0 + 4);
#pragma unroll
    for (int q = 0; q < 4; ++q) {
        at2[q][0] = (_Float16)tmp8[2 * q];
        at2[q][1] = (_Float16)tmp8[2 * q + 1];
    }
    *(float4*)&b8[0] = *(const float4*)(bias + c0);
    *(float4*)&b8[4] = *(const float4*)(bias + c0 + 4);
}

// ======== FUSED: layer-1 aggregate + layer-2 node transform (16 nodes/block) ========
// Round-11 structure (grid 3125, LDS 4.6KB -- occupancy-friendly, best measured).
// Epilogue weight fragments loaded BEFORE the barrier and pinned live with an
// empty asm (compiler would otherwise sink the loads past the barrier): their
// L2 latency hides under the aggregation phase.
__global__ __launch_bounds__(256) void gat_agg1_t128_kernel(
        const __half* __restrict__ xl, const __half* __restrict__ xr,
        const float* __restrict__ We, const float* __restrict__ att,
        const float* __restrict__ bias,
        const unsigned* __restrict__ packed, const int* __restrict__ row_ptr,
        const __half* __restrict__ Wcat, const float* __restrict__ bl2,
        const float* __restrict__ br2,
        __half* __restrict__ xl2, __half* __restrict__ xr2, int n) {
    __shared__ __align__(16) __half hs[16 * TPAD];
    int t = threadIdx.x;
    int tl = t & 63, wid = t >> 6;
    int g = tl >> 4, u = tl & 15, c0 = u * 8;
    hh2 we2[4], at2[4];
    float b8[8];
    load_edge_consts(We, att, bias, c0, we2, at2, b8);

    // ---- epilogue constants: issue early, pin live across the barrier ----
    int lrow = tl & 15, lgr = tl >> 4;
    int colbase = wid * 64;
    half8 bfrag[4][4];
    const __half* wp = Wcat + (size_t)(colbase + lrow) * HCDIM + lgr * 8;
#pragma unroll
    for (int ct = 0; ct < 4; ++ct)
#pragma unroll
        for (int ks = 0; ks < 4; ++ks)
            bfrag[ct][ks] = *(const half8*)(wp + ct * 16 * HCDIM + ks * 32);
    float bv[4];
#pragma unroll
    for (int ct = 0; ct < 4; ++ct) {
        int col = colbase + ct * 16 + lrow;
        bv[ct] = (col < HCDIM) ? bl2[col] : br2[col - HCDIM];
    }
#pragma unroll
    for (int ct = 0; ct < 4; ++ct) {
#pragma unroll
        for (int ks = 0; ks < 4; ++ks) asm volatile("" : "+v"(bfrag[ct][ks]));
        asm volatile("" : "+v"(bv[ct]));
    }

    int base = blockIdx.x * 16;
    int rel = wid * 4 + g;
    int node = base + rel;
    half8 hv = aggregate_node<4>(node, n, xl + c0, xr, c0, packed, row_ptr, we2, at2, b8);
    *(half8*)&hs[rel * TPAD + c0] = hv;
    __syncthreads();

    // layer-2 transform: single 16-row tile, wave owns 64 output cols
    __half* dstp = (colbase < HCDIM) ? xl2 : xr2;
    int cb = (colbase < HCDIM) ? colbase : colbase - HCDIM;

    half8 afrag[4];
    const __half* ap = &hs[lrow * TPAD + lgr * 8];
#pragma unroll
    for (int ks = 0; ks < 4; ++ks) afrag[ks] = *(const half8*)(ap + ks * 32);
    floatx4 acc[4];
#pragma unroll
    for (int ct = 0; ct < 4; ++ct) {
        acc[ct] = (floatx4){0.f, 0.f, 0.f, 0.f};
#pragma unroll
        for (int ks = 0; ks < 4; ++ks)
            acc[ct] = __builtin_amdgcn_mfma_f32_16x16x32_f16(afrag[ks], bfrag[ct][ks],
                                                             acc[ct], 0, 0, 0);
    }
    int rowb = base + lgr * 4;
#pragma unroll
    for (int ct = 0; ct < 4; ++ct) {
        int col = cb + ct * 16 + lrow;
#pragma unroll
        for (int r = 0; r < 4; ++r) {
            int node2 = rowb + r;
            if (node2 < n) dstp[(size_t)node2 * HCDIM + col] = __float2half(acc[ct][r] + bv[ct]);
        }
    }
}

// ======== FUSED: layer-2 aggregate + MLP head (16 nodes/block) ========
__global__ __launch_bounds__(256) void gat_agg2_mlp_kernel(
        const __half* __restrict__ xl, const __half* __restrict__ xr,
        const float* __restrict__ We, const float* __restrict__ att,
        const float* __restrict__ bias,
        const unsigned* __restrict__ packed, const int* __restrict__ row_ptr,
        const __half* __restrict__ W1f, const float* __restrict__ c1,
        const __half* __restrict__ W2f, const float* __restrict__ c2,
        const float* __restrict__ W3, const float* __restrict__ c3,
        float* __restrict__ out, int n) {
    __shared__ __align__(16) __half hs[16 * TPAD];
    __shared__ __align__(16) __half a1[16 * A1S];
    __shared__ __align__(16) __half a2[16 * A1S];
    int t = threadIdx.x;
    int tl = t & 63, wid = t >> 6;
    int g = tl >> 4, u = tl & 15, c0 = u * 8;
    hh2 we2[4], at2[4];
    float b8[8];
    load_edge_consts(We, att, bias, c0, we2, at2, b8);

    int lrow = tl & 15, lgr = tl >> 4;
    // ---- hoist MLP layer-1 weights (waves 0,1), pin live across barrier ----
    half8 w1frag[4];
    float cc1 = 0.f;
    if (wid < 2) {
        const __half* wp = W1f + (size_t)(wid * 16 + lrow) * HCDIM + lgr * 8;
#pragma unroll
        for (int ks = 0; ks < 4; ++ks) w1frag[ks] = *(const half8*)(wp + ks * 32);
        cc1 = c1[wid * 16 + lrow];
#pragma unroll
        for (int ks = 0; ks < 4; ++ks) asm volatile("" : "+v"(w1frag[ks]));
        asm volatile("" : "+v"(cc1));
    }

    int base = blockIdx.x * 16;
    int rel = wid * 4 + g;
    int node = base + rel;
    half8 hv = aggregate_node<16>(node, n, xl + c0, xr, c0, packed, row_ptr, we2, at2, b8);
    *(half8*)&hs[rel * TPAD + c0] = hv;
    __syncthreads();

    // layer1: [16,128] x W1^T -> relu -> a1 [16,32]  (waves 0,1; ct = wid)
    if (wid < 2) {
        int ct = wid;
        floatx4 acc = (floatx4){0.f, 0.f, 0.f, 0.f};
        const __half* ap = &hs[lrow * TPAD + lgr * 8];
#pragma unroll
        for (int ks = 0; ks < 4; ++ks) {
            half8 af = *(const half8*)(ap + ks * 32);
            acc = __builtin_amdgcn_mfma_f32_16x16x32_f16(af, w1frag[ks], acc, 0, 0, 0);
        }
        int col = ct * 16 + lrow;
#pragma unroll
        for (int r = 0; r < 4; ++r)
            a1[(lgr * 4 + r) * A1S + col] = __float2half(fmaxf(acc[r] + cc1, 0.f));
    }
    __syncthreads();
    // layer2: [16,32] x W2^T (K=32, one MFMA) -> relu -> a2
    if (wid < 2) {
        int ct = wid;
        half8 af = *(const half8*)&a1[lrow * A1S + lgr * 8];
        half8 bf = *(const half8*)(W2f + (size_t)(ct * 16 + lrow) * 32 + lgr * 8);
        floatx4 acc = __builtin_amdgcn_mfma_f32_16x16x32_f16(af, bf,
                                                             (floatx4){0.f, 0.f, 0.f, 0.f}, 0, 0, 0);
        int col = ct * 16 + lrow;
        float cc = c2[col];
#pragma unroll
        for (int r = 0; r < 4; ++r)
            a2[(lgr * 4 + r) * A1S + col] = __float2half(fmaxf(acc[r] + cc, 0.f));
    }
    __syncthreads();
    // layer3: 16x2 outputs, 32-length f32 dots
    if (t < 32) {
        int rel3 = t >> 1, oo = t & 1;
        int node3 = base + rel3;
        if (node3 < n) {
            float s = c3[oo];
            const __half* ar = &a2[rel3 * A1S];
#pragma unroll
            for (int i = 0; i < 32; ++i) s = fmaf(W3[oo * 32 + i], __half2float(ar[i]), s);
            out[(size_t)node3 * 2 + oo] = s;
        }
    }
}

extern "C" void kernel_launch(void* const* d_in, const int* in_sizes, int n_in,
                              void* d_out, int out_size, void* d_ws, size_t ws_size,
                              hipStream_t stream) {
    const float* x      = (const float*)d_in[0];
    const int*   eidx   = (const int*)d_in[1];
    const float* eattr  = (const float*)d_in[2];
    const float* Wl1    = (const float*)d_in[3];
    const float* bl1    = (const float*)d_in[4];
    const float* Wr1    = (const float*)d_in[5];
    const float* br1    = (const float*)d_in[6];
    const float* We1    = (const float*)d_in[7];
    const float* att1   = (const float*)d_in[8];
    const float* b1     = (const float*)d_in[9];
    const float* Wl2    = (const float*)d_in[10];
    const float* bl2    = (const float*)d_in[11];
    const float* Wr2    = (const float*)d_in[12];
    const float* br2    = (const float*)d_in[13];
    const float* We2    = (const float*)d_in[14];
    const float* att2   = (const float*)d_in[15];
    const float* b2     = (const float*)d_in[16];
    const float* W1     = (const float*)d_in[17];
    const float* c1     = (const float*)d_in[18];
    const float* W2     = (const float*)d_in[19];
    const float* c2     = (const float*)d_in[20];
    const float* W3     = (const float*)d_in[21];
    const float* c3     = (const float*)d_in[22];
    float* out = (float*)d_out;

    const int N = in_sizes[0] / 16;
    const int E = in_sizes[2];
    const int* src = eidx;
    const int* dst = eidx + E;

    // ---- workspace carve-up (256B aligned) ----
    char* w = (char*)d_ws;
    size_t off = 0;
    auto carve = [&](size_t bytes) -> void* {
        void* p = w + off;
        off = (off + bytes + 255) & ~(size_t)255;
        return p;
    };
    __half* xl1     = (__half*)carve((size_t)N * HCDIM * sizeof(__half));
    __half* xr1     = (__half*)carve((size_t)N * HCDIM * sizeof(__half));
    __half* xl2     = (__half*)carve((size_t)N * HCDIM * sizeof(__half));
    __half* xr2     = (__half*)carve((size_t)N * HCDIM * sizeof(__half));
    int*    row_ptr = (int*)carve((size_t)(N + 1) * sizeof(int));
    int*    bucket_cursor = (int*)carve(NBUCK * sizeof(int));
    int2*   binned  = (int2*)carve((size_t)NBUCK * BCAP * sizeof(int2));
    unsigned* packed = (unsigned*)carve((size_t)E * sizeof(unsigned));
    __half* Wcat    = (__half*)carve((size_t)256 * HCDIM * sizeof(__half));
    __half* Wcat1   = (__half*)carve((size_t)256 * 32 * sizeof(__half));
    __half* W1f     = (__half*)carve((size_t)32 * HCDIM * sizeof(__half));
    __half* W2f     = (__half*)carve((size_t)32 * 32 * sizeof(__half));
    (void)ws_size; (void)n_in; (void)out_size;

    const int nb = (N + 255) / 256;
    const int nchunk = (E + CHUNK - 1) / CHUNK;

    // K1: weight prep + cursor zero
    convert_w_all_kernel<<<180, 256, 0, stream>>>(Wl1, Wr1, Wcat1, Wl2, Wr2, Wcat,
                                                  W1, W1f, W2, W2f, bucket_cursor);
    // K2-K3: CSR build
    bin_kernel<<<nchunk, 256, 0, stream>>>(src, dst, eattr, bucket_cursor, binned, E);
    scatter2_kernel<<<nb, 256, 0, stream>>>(binned, bucket_cursor, packed, row_ptr, N);

    // K4: layer-1 node transform
    transform16_mfma_kernel<<<(N + 63) / 64, 256, 0, stream>>>(
        x, Wcat1, bl1, br1, xl1, xr1, N);

    // K5: layer-1 aggregate fused with layer-2 transform (16 nodes/block)
    gat_agg1_t128_kernel<<<(N + 15) / 16, 256, 0, stream>>>(
        xl1, xr1, We1, att1, b1, packed, row_ptr, Wcat, bl2, br2, xl2, xr2, N);

    // K6: layer-2 aggregate fused with MLP head (16 nodes/block)
    gat_agg2_mlp_kernel<<<(N + 15) / 16, 256, 0, stream>>>(
        xl2, xr2, We2, att2, b2, packed, row_ptr, W1f, c1, W2f, c2, W3, c3, out, N);
}

// Round 15
// 253.738 us; speedup vs baseline: 1.0634x; 1.0634x over previous
//
#include <hip/hip_runtime.h>
#include <hip/hip_fp16.h>
#include <math.h>

#define HCDIM 128
#define LEAKY 0.2f
#define NBUCK 256
#define CHUNK 2048
#define BCAP 5120  // per-bucket capacity; mean 4100, sigma 64 -> 16-sigma slack
#define TPAD 136   // halves; 272B row stride
#define A1S 40

typedef _Float16 half8 __attribute__((ext_vector_type(8)));
typedef _Float16 hh2 __attribute__((ext_vector_type(2)));
typedef float floatx4 __attribute__((ext_vector_type(4)));

// ================= CSR build: binned counting sort =================
__global__ void convert_w_all_kernel(const float* __restrict__ Wl1, const float* __restrict__ Wr1,
                                     __half* __restrict__ Wcat1,
                                     const float* __restrict__ Wl2, const float* __restrict__ Wr2,
                                     __half* __restrict__ Wcat2,
                                     const float* __restrict__ W1, __half* __restrict__ W1f,
                                     const float* __restrict__ W2, __half* __restrict__ W2f,
                                     int* __restrict__ bucket_cursor) {
    int i = blockIdx.x * 256 + threadIdx.x;  // 0 .. 46079
    if (blockIdx.x == 0) bucket_cursor[threadIdx.x] = 0;
    if (i < 8192) {
        int row = i >> 5, c = i & 31;
        float v = 0.f;
        if (c < 16) v = (row < 128) ? Wl1[row * 16 + c] : Wr1[(row - 128) * 16 + c];
        Wcat1[i] = __float2half(v);
    } else if (i < 40960) {
        int j = i - 8192;
        float v = (j < 128 * HCDIM) ? Wl2[j] : Wr2[j - 128 * HCDIM];
        Wcat2[j] = __float2half(v);
    } else if (i < 45056) {
        int j = i - 40960;
        W1f[j] = __float2half(W1[j]);
    } else if (i < 46080) {
        int j = i - 45056;
        W2f[j] = __float2half(W2[j]);
    }
}

__global__ __launch_bounds__(256) void bin_kernel(
        const int* __restrict__ src, const int* __restrict__ dst,
        const float* __restrict__ eattr, int* __restrict__ bucket_cursor,
        int2* __restrict__ binned, int E) {
    __shared__ int hist[NBUCK];
    __shared__ int hist2[NBUCK];
    __shared__ int gbase[NBUCK];
    int t = threadIdx.x;
    int e0 = blockIdx.x * CHUNK;
    int cnt = min(CHUNK, E - e0);
    hist[t] = 0;
    hist2[t] = 0;
    __syncthreads();
    for (int i = t; i < cnt; i += 256) atomicAdd(&hist[((unsigned)dst[e0 + i]) >> 8], 1);
    __syncthreads();
    if (hist[t]) gbase[t] = atomicAdd(&bucket_cursor[t], hist[t]);
    __syncthreads();
    for (int i = t; i < cnt; i += 256) {
        int d = dst[e0 + i];
        int b = ((unsigned)d) >> 8;
        unsigned sv = (unsigned)src[e0 + i] & 0xFFFFu;
        __half eh = __float2half(eattr[e0 + i]);
        int r = atomicAdd(&hist2[b], 1);
        int2 rec;
        rec.x = (int)(sv | ((unsigned)__half_as_ushort(eh) << 16));
        rec.y = d;
        binned[(size_t)b * BCAP + gbase[b] + r] = rec;
    }
}

__global__ __launch_bounds__(256) void scatter2_kernel(
        const int2* __restrict__ binned, const int* __restrict__ bucket_cursor,
        unsigned* __restrict__ packed, int* __restrict__ row_ptr, int n) {
    __shared__ int bsc[NBUCK];
    __shared__ int degl[NBUCK];
    __shared__ int scn[NBUCK];
    __shared__ int cur[NBUCK];
    int t = threadIdx.x;
    int b = blockIdx.x;
    int n0 = b << 8;
    int nodes = min(256, n - n0);
    size_t sbase = (size_t)b * BCAP;
    int cnt = bucket_cursor[b];
    bsc[t] = bucket_cursor[t];
    degl[t] = 0;
    __syncthreads();
    for (int off = 1; off < NBUCK; off <<= 1) {
        int add = (t >= off) ? bsc[t - off] : 0;
        __syncthreads();
        bsc[t] += add;
        __syncthreads();
    }
    int w0 = bsc[b] - cnt;
    for (int i = t; i < cnt; i += 256) atomicAdd(&degl[binned[sbase + i].y & 255], 1);
    __syncthreads();
    int v = degl[t];
    scn[t] = v;
    __syncthreads();
    for (int off = 1; off < NBUCK; off <<= 1) {
        int add = (t >= off) ? scn[t - off] : 0;
        __syncthreads();
        scn[t] += add;
        __syncthreads();
    }
    int pos0 = w0 + scn[t] - v;
    cur[t] = pos0;
    if (t < nodes) row_ptr[n0 + t] = pos0;
    if (t == nodes - 1 && n0 + nodes == n) row_ptr[n] = w0 + cnt;
    __syncthreads();
    for (int i = t; i < cnt; i += 256) {
        int2 rec = binned[sbase + i];
        int p = atomicAdd(&cur[rec.y & 255], 1);
        packed[p] = (unsigned)rec.x;
    }
}

// ---------------- Layer 1 node transform via MFMA: x[N,16] -> xl, xr (fp16) ----------------
#define T16PAD 40
__global__ __launch_bounds__(256) void transform16_mfma_kernel(
        const float* __restrict__ x, const __half* __restrict__ Wcat1,
        const float* __restrict__ bl, const float* __restrict__ br,
        __half* __restrict__ xl, __half* __restrict__ xr, int n) {
    __shared__ __align__(16) __half ax[64 * T16PAD];
    int t = threadIdx.x;
    int base = blockIdx.x * 64;

    {
        int row = t >> 2, cg = t & 3;
        float4 v;
        if (base + row < n) v = *(const float4*)(x + (size_t)(base + row) * 16 + cg * 4);
        else v = make_float4(0.f, 0.f, 0.f, 0.f);
        __half2* p = (__half2*)&ax[row * T16PAD + cg * 4];
        p[0] = __floats2half2_rn(v.x, v.y);
        p[1] = __floats2half2_rn(v.z, v.w);
        __half2* z = (__half2*)&ax[row * T16PAD + 16 + cg * 4];
        z[0] = __floats2half2_rn(0.f, 0.f);
        z[1] = __floats2half2_rn(0.f, 0.f);
    }
    __syncthreads();

    int wid = t >> 6, l = t & 63;
    int lrow = l & 15, lgr = l >> 4;
    int colbase = wid * 64;

    half8 bfrag[4];
    const __half* wp = Wcat1 + (size_t)(colbase + lrow) * 32 + lgr * 8;
#pragma unroll
    for (int ct = 0; ct < 4; ++ct) bfrag[ct] = *(const half8*)(wp + ct * 16 * 32);

    float bv[4];
#pragma unroll
    for (int ct = 0; ct < 4; ++ct) {
        int col = colbase + ct * 16 + lrow;
        bv[ct] = (col < HCDIM) ? bl[col] : br[col - HCDIM];
    }
    __half* dstp = (colbase < HCDIM) ? xl : xr;
    int cb = (colbase < HCDIM) ? colbase : colbase - HCDIM;

#pragma unroll
    for (int rt = 0; rt < 4; ++rt) {
        half8 afrag = *(const half8*)&ax[(rt * 16 + lrow) * T16PAD + lgr * 8];
        floatx4 acc[4];
#pragma unroll
        for (int ct = 0; ct < 4; ++ct) {
            acc[ct] = (floatx4){0.f, 0.f, 0.f, 0.f};
            acc[ct] = __builtin_amdgcn_mfma_f32_16x16x32_f16(afrag, bfrag[ct], acc[ct], 0, 0, 0);
        }
        int rowb = base + rt * 16 + lgr * 4;
#pragma unroll
        for (int ct = 0; ct < 4; ++ct) {
            int col = cb + ct * 16 + lrow;
#pragma unroll
            for (int r = 0; r < 4; ++r) {
                int node = rowb + r;
                if (node < n) dstp[(size_t)node * HCDIM + col] = __float2half(acc[ct][r] + bv[ct]);
            }
        }
    }
}

// ======== shared edge-aggregation core (node-per-16-lane-group, depth-3) ========
template <int CTRL>
__device__ inline float dpp_radd(float x) {
    int y = __builtin_amdgcn_update_dpp(0, __float_as_int(x), CTRL, 0xF, 0xF, true);
    return x + __int_as_float(y);
}

template <int NMASK>
__device__ inline void edge_update_pk(uint4 rowbits, _Float16 eah, bool valid,
                                      const hh2* __restrict__ xr2,
                                      const hh2* __restrict__ we2,
                                      const hh2* __restrict__ at2,
                                      float& d, float* __restrict__ acc) {
    const hh2* xv2 = (const hh2*)&rowbits;
    float p = 0.f;
#pragma unroll
    for (int q = 0; q < 4; ++q) {
        hh2 m = xv2[q] + xr2[q] + eah * we2[q];
        hh2 lk = __builtin_elementwise_max(m, (_Float16)LEAKY * m);  // leaky_relu(x,0.2)
#if __has_builtin(__builtin_amdgcn_fdot2)
        p = __builtin_amdgcn_fdot2(at2[q], lk, p, false);
#else
        p = fmaf((float)at2[q][0], (float)lk[0], fmaf((float)at2[q][1], (float)lk[1], p));
#endif
    }
    p = dpp_radd<0xB1>(p);   // quad_perm [1,0,3,2]
    p = dpp_radd<0x4E>(p);   // quad_perm [2,3,0,1]
    if constexpr (NMASK == 16) {
        p = dpp_radd<0x124>(p);  // row_ror:4
        p = dpp_radd<0x128>(p);  // row_ror:8
    }
    float w = valid ? __expf(p) : 0.f;
    d += w;
    const _Float16* xvh = (const _Float16*)&rowbits;
#pragma unroll
    for (int k = 0; k < 8; ++k) acc[k] = fmaf(w, (float)xvh[k], acc[k]);
}

__device__ inline _Float16 unpack_ea(unsigned pe) {
    ushort hb = (ushort)(pe >> 16);
    _Float16 r;
    __builtin_memcpy(&r, &hb, 2);
    return r;
}

template <int NMASK>
__device__ inline half8 aggregate_node(int node, int n,
                                       const __half* __restrict__ xlc,
                                       const __half* __restrict__ xr, int c0,
                                       const unsigned* __restrict__ packed,
                                       const int* __restrict__ row_ptr,
                                       const hh2* __restrict__ we2,
                                       const hh2* __restrict__ at2,
                                       const float* __restrict__ b8) {
    int nodec = min(node, n - 1);
    uint4 xrbits = *(const uint4*)(xr + (size_t)nodec * HCDIM + c0);
    const hh2* xr2 = (const hh2*)&xrbits;
    int beg = row_ptr[nodec], end = row_ptr[nodec + 1];
    float d = 0.f, acc[8];
#pragma unroll
    for (int k = 0; k < 8; ++k) acc[k] = 0.f;
    bool has = (node < n) && (end > beg);
    if (has) {
        int last = end - 1;
        bool vA = true, vB = beg + 1 < end;
        bool v1A = beg + 2 < end, v1B = beg + 3 < end;
        unsigned pe0A = packed[beg];
        unsigned pe0B = packed[min(beg + 1, last)];
        unsigned pe1A = packed[min(beg + 2, last)];
        unsigned pe1B = packed[min(beg + 3, last)];
        uint4 r0A = *(const uint4*)(xlc + (size_t)(pe0A & 0xFFFFu) * HCDIM);
        uint4 r0B = *(const uint4*)(xlc + (size_t)(pe0B & 0xFFFFu) * HCDIM);
        uint4 r1A = *(const uint4*)(xlc + (size_t)(pe1A & 0xFFFFu) * HCDIM);
        uint4 r1B = *(const uint4*)(xlc + (size_t)(pe1B & 0xFFFFu) * HCDIM);
        int j = beg;
        while (true) {
            bool v2A = j + 4 < end, v2B = j + 5 < end;
            unsigned pe2A = packed[min(j + 4, last)];
            unsigned pe2B = packed[min(j + 5, last)];
            uint4 r2A = *(const uint4*)(xlc + (size_t)(pe2A & 0xFFFFu) * HCDIM);
            uint4 r2B = *(const uint4*)(xlc + (size_t)(pe2B & 0xFFFFu) * HCDIM);
            edge_update_pk<NMASK>(r0A, unpack_ea(pe0A), vA, xr2, we2, at2, d, acc);
            edge_update_pk<NMASK>(r0B, unpack_ea(pe0B), vB, xr2, we2, at2, d, acc);
            pe0A = pe1A; pe0B = pe1B; r0A = r1A; r0B = r1B; vA = v1A; vB = v1B;
            pe1A = pe2A; pe1B = pe2B; r1A = r2A; r1B = r2B; v1A = v2A; v1B = v2B;
            j += 2;
            if (!vA) break;
        }
    }
    float inv = has ? __frcp_rn(d) : 0.f;
    half8 hv;
#pragma unroll
    for (int k = 0; k < 8; ++k) {
        float v = has ? acc[k] * inv + b8[k] : b8[k];
        v = v > 0.f ? v : expm1f(v);  // ELU
        hv[k] = (_Float16)v;
    }
    return hv;
}

__device__ inline void load_edge_consts(const float* We, const float* att,
                                        const float* bias, int c0,
                                        hh2* we2, hh2* at2, float* b8) {
    float tmp8[8];
    *(float4*)&tmp8[0] = *(const float4*)(We + c0);
    *(float4*)&tmp8[4] = *(const float4*)(We + c0 + 4);
#pragma unroll
    for (int q = 0; q < 4; ++q) {
        we2[q][0] = (_Float16)tmp8[2 * q];
        we2[q][1] = (_Float16)tmp8[2 * q + 1];
    }
    *(float4*)&tmp8[0] = *(const float4*)(att + c0);
    *(float4*)&tmp8[4] = *(const float4*)(att + c0 + 4);
#pragma unroll
    for (int q = 0; q < 4; ++q) {
        at2[q][0] = (_Float16)tmp8[2 * q];
        at2[q][1] = (_Float16)tmp8[2 * q + 1];
    }
    *(float4*)&b8[0] = *(const float4*)(bias + c0);
    *(float4*)&b8[4] = *(const float4*)(bias + c0 + 4);
}

// ======== FUSED: layer-1 aggregate + layer-2 node transform (16 nodes/block) ========
// Best-measured configuration (251.7us): grid 3125, LDS 4.6KB, VGPR ~60,
// epilogue weights loaded AFTER the barrier. Both perturbations were measured
// and regressed: 64-node blocks (r12: LDS 17.4KB -> occ 25%, +9us) and
// pre-barrier weight hoist (r14: VGPR 80 -> occ 28%, +13us). The aggregation
// phase is occupancy-dominated; keep it lean.
__global__ __launch_bounds__(256) void gat_agg1_t128_kernel(
        const __half* __restrict__ xl, const __half* __restrict__ xr,
        const float* __restrict__ We, const float* __restrict__ att,
        const float* __restrict__ bias,
        const unsigned* __restrict__ packed, const int* __restrict__ row_ptr,
        const __half* __restrict__ Wcat, const float* __restrict__ bl2,
        const float* __restrict__ br2,
        __half* __restrict__ xl2, __half* __restrict__ xr2, int n) {
    __shared__ __align__(16) __half hs[16 * TPAD];
    int t = threadIdx.x;
    int tl = t & 63, wid = t >> 6;
    int g = tl >> 4, u = tl & 15, c0 = u * 8;
    hh2 we2[4], at2[4];
    float b8[8];
    load_edge_consts(We, att, bias, c0, we2, at2, b8);

    int base = blockIdx.x * 16;
    int rel = wid * 4 + g;
    int node = base + rel;
    half8 hv = aggregate_node<4>(node, n, xl + c0, xr, c0, packed, row_ptr, we2, at2, b8);
    *(half8*)&hs[rel * TPAD + c0] = hv;
    __syncthreads();

    // layer-2 transform: single 16-row tile, wave owns 64 output cols
    int lrow = tl & 15, lgr = tl >> 4;
    int colbase = wid * 64;
    half8 bfrag[4][4];
    const __half* wp = Wcat + (size_t)(colbase + lrow) * HCDIM + lgr * 8;
#pragma unroll
    for (int ct = 0; ct < 4; ++ct)
#pragma unroll
        for (int ks = 0; ks < 4; ++ks)
            bfrag[ct][ks] = *(const half8*)(wp + ct * 16 * HCDIM + ks * 32);

    float bv[4];
#pragma unroll
    for (int ct = 0; ct < 4; ++ct) {
        int col = colbase + ct * 16 + lrow;
        bv[ct] = (col < HCDIM) ? bl2[col] : br2[col - HCDIM];
    }
    __half* dstp = (colbase < HCDIM) ? xl2 : xr2;
    int cb = (colbase < HCDIM) ? colbase : colbase - HCDIM;

    half8 afrag[4];
    const __half* ap = &hs[lrow * TPAD + lgr * 8];
#pragma unroll
    for (int ks = 0; ks < 4; ++ks) afrag[ks] = *(const half8*)(ap + ks * 32);
    floatx4 acc[4];
#pragma unroll
    for (int ct = 0; ct < 4; ++ct) {
        acc[ct] = (floatx4){0.f, 0.f, 0.f, 0.f};
#pragma unroll
        for (int ks = 0; ks < 4; ++ks)
            acc[ct] = __builtin_amdgcn_mfma_f32_16x16x32_f16(afrag[ks], bfrag[ct][ks],
                                                             acc[ct], 0, 0, 0);
    }
    int rowb = base + lgr * 4;
#pragma unroll
    for (int ct = 0; ct < 4; ++ct) {
        int col = cb + ct * 16 + lrow;
#pragma unroll
        for (int r = 0; r < 4; ++r) {
            int node2 = rowb + r;
            if (node2 < n) dstp[(size_t)node2 * HCDIM + col] = __float2half(acc[ct][r] + bv[ct]);
        }
    }
}

// ======== FUSED: layer-2 aggregate + MLP head (16 nodes/block) ========
__global__ __launch_bounds__(256) void gat_agg2_mlp_kernel(
        const __half* __restrict__ xl, const __half* __restrict__ xr,
        const float* __restrict__ We, const float* __restrict__ att,
        const float* __restrict__ bias,
        const unsigned* __restrict__ packed, const int* __restrict__ row_ptr,
        const __half* __restrict__ W1f, const float* __restrict__ c1,
        const __half* __restrict__ W2f, const float* __restrict__ c2,
        const float* __restrict__ W3, const float* __restrict__ c3,
        float* __restrict__ out, int n) {
    __shared__ __align__(16) __half hs[16 * TPAD];
    __shared__ __align__(16) __half a1[16 * A1S];
    __shared__ __align__(16) __half a2[16 * A1S];
    int t = threadIdx.x;
    int tl = t & 63, wid = t >> 6;
    int g = tl >> 4, u = tl & 15, c0 = u * 8;
    hh2 we2[4], at2[4];
    float b8[8];
    load_edge_consts(We, att, bias, c0, we2, at2, b8);

    int base = blockIdx.x * 16;
    int rel = wid * 4 + g;
    int node = base + rel;
    half8 hv = aggregate_node<16>(node, n, xl + c0, xr, c0, packed, row_ptr, we2, at2, b8);
    *(half8*)&hs[rel * TPAD + c0] = hv;
    __syncthreads();

    int lrow = tl & 15, lgr = tl >> 4;
    // layer1: [16,128] x W1^T -> relu -> a1 [16,32]  (waves 0,1; ct = wid)
    if (wid < 2) {
        int ct = wid;
        floatx4 acc = (floatx4){0.f, 0.f, 0.f, 0.f};
        const __half* wp = W1f + (size_t)(ct * 16 + lrow) * HCDIM + lgr * 8;
        const __half* ap = &hs[lrow * TPAD + lgr * 8];
#pragma unroll
        for (int ks = 0; ks < 4; ++ks) {
            half8 af = *(const half8*)(ap + ks * 32);
            half8 bf = *(const half8*)(wp + ks * 32);
            acc = __builtin_amdgcn_mfma_f32_16x16x32_f16(af, bf, acc, 0, 0, 0);
        }
        int col = ct * 16 + lrow;
        float cc = c1[col];
#pragma unroll
        for (int r = 0; r < 4; ++r)
            a1[(lgr * 4 + r) * A1S + col] = __float2half(fmaxf(acc[r] + cc, 0.f));
    }
    __syncthreads();
    // layer2: [16,32] x W2^T (K=32, one MFMA) -> relu -> a2
    if (wid < 2) {
        int ct = wid;
        half8 af = *(const half8*)&a1[lrow * A1S + lgr * 8];
        half8 bf = *(const half8*)(W2f + (size_t)(ct * 16 + lrow) * 32 + lgr * 8);
        floatx4 acc = __builtin_amdgcn_mfma_f32_16x16x32_f16(af, bf,
                                                             (floatx4){0.f, 0.f, 0.f, 0.f}, 0, 0, 0);
        int col = ct * 16 + lrow;
        float cc = c2[col];
#pragma unroll
        for (int r = 0; r < 4; ++r)
            a2[(lgr * 4 + r) * A1S + col] = __float2half(fmaxf(acc[r] + cc, 0.f));
    }
    __syncthreads();
    // layer3: 16x2 outputs, 32-length f32 dots
    if (t < 32) {
        int rel3 = t >> 1, oo = t & 1;
        int node3 = base + rel3;
        if (node3 < n) {
            float s = c3[oo];
            const __half* ar = &a2[rel3 * A1S];
#pragma unroll
            for (int i = 0; i < 32; ++i) s = fmaf(W3[oo * 32 + i], __half2float(ar[i]), s);
            out[(size_t)node3 * 2 + oo] = s;
        }
    }
}

extern "C" void kernel_launch(void* const* d_in, const int* in_sizes, int n_in,
                              void* d_out, int out_size, void* d_ws, size_t ws_size,
                              hipStream_t stream) {
    const float* x      = (const float*)d_in[0];
    const int*   eidx   = (const int*)d_in[1];
    const float* eattr  = (const float*)d_in[2];
    const float* Wl1    = (const float*)d_in[3];
    const float* bl1    = (const float*)d_in[4];
    const float* Wr1    = (const float*)d_in[5];
    const float* br1    = (const float*)d_in[6];
    const float* We1    = (const float*)d_in[7];
    const float* att1   = (const float*)d_in[8];
    const float* b1     = (const float*)d_in[9];
    const float* Wl2    = (const float*)d_in[10];
    const float* bl2    = (const float*)d_in[11];
    const float* Wr2    = (const float*)d_in[12];
    const float* br2    = (const float*)d_in[13];
    const float* We2    = (const float*)d_in[14];
    const float* att2   = (const float*)d_in[15];
    const float* b2     = (const float*)d_in[16];
    const float* W1     = (const float*)d_in[17];
    const float* c1     = (const float*)d_in[18];
    const float* W2     = (const float*)d_in[19];
    const float* c2     = (const float*)d_in[20];
    const float* W3     = (const float*)d_in[21];
    const float* c3     = (const float*)d_in[22];
    float* out = (float*)d_out;

    const int N = in_sizes[0] / 16;
    const int E = in_sizes[2];
    const int* src = eidx;
    const int* dst = eidx + E;

    // ---- workspace carve-up (256B aligned) ----
    char* w = (char*)d_ws;
    size_t off = 0;
    auto carve = [&](size_t bytes) -> void* {
        void* p = w + off;
        off = (off + bytes + 255) & ~(size_t)255;
        return p;
    };
    __half* xl1     = (__half*)carve((size_t)N * HCDIM * sizeof(__half));
    __half* xr1     = (__half*)carve((size_t)N * HCDIM * sizeof(__half));
    __half* xl2     = (__half*)carve((size_t)N * HCDIM * sizeof(__half));
    __half* xr2     = (__half*)carve((size_t)N * HCDIM * sizeof(__half));
    int*    row_ptr = (int*)carve((size_t)(N + 1) * sizeof(int));
    int*    bucket_cursor = (int*)carve(NBUCK * sizeof(int));
    int2*   binned  = (int2*)carve((size_t)NBUCK * BCAP * sizeof(int2));
    unsigned* packed = (unsigned*)carve((size_t)E * sizeof(unsigned));
    __half* Wcat    = (__half*)carve((size_t)256 * HCDIM * sizeof(__half));
    __half* Wcat1   = (__half*)carve((size_t)256 * 32 * sizeof(__half));
    __half* W1f     = (__half*)carve((size_t)32 * HCDIM * sizeof(__half));
    __half* W2f     = (__half*)carve((size_t)32 * 32 * sizeof(__half));
    (void)ws_size; (void)n_in; (void)out_size;

    const int nb = (N + 255) / 256;
    const int nchunk = (E + CHUNK - 1) / CHUNK;

    // K1: weight prep + cursor zero
    convert_w_all_kernel<<<180, 256, 0, stream>>>(Wl1, Wr1, Wcat1, Wl2, Wr2, Wcat,
                                                  W1, W1f, W2, W2f, bucket_cursor);
    // K2-K3: CSR build
    bin_kernel<<<nchunk, 256, 0, stream>>>(src, dst, eattr, bucket_cursor, binned, E);
    scatter2_kernel<<<nb, 256, 0, stream>>>(binned, bucket_cursor, packed, row_ptr, N);

    // K4: layer-1 node transform
    transform16_mfma_kernel<<<(N + 63) / 64, 256, 0, stream>>>(
        x, Wcat1, bl1, br1, xl1, xr1, N);

    // K5: layer-1 aggregate fused with layer-2 transform (16 nodes/block)
    gat_agg1_t128_kernel<<<(N + 15) / 16, 256, 0, stream>>>(
        xl1, xr1, We1, att1, b1, packed, row_ptr, Wcat, bl2, br2, xl2, xr2, N);

    // K6: layer-2 aggregate fused with MLP head (16 nodes/block)
    gat_agg2_mlp_kernel<<<(N + 15) / 16, 256, 0, stream>>>(
        xl2, xr2, We2, att2, b2, packed, row_ptr, W1f, c1, W2f, c2, W3, c3, out, N);
}